// Round 7
// baseline (3147.530 us; speedup 1.0000x reference)
//
#include <hip/hip_runtime.h>

typedef unsigned short u16;
using bf16x8 = __attribute__((ext_vector_type(8))) short;
using u16x8  = __attribute__((ext_vector_type(8))) unsigned short;
using f32x4  = __attribute__((ext_vector_type(4))) float;

#define NN 50000
#define NPAD 50176   // 196 * 256

__device__ __forceinline__ u16 f2b(float f) {
  union { float f; unsigned u; } x; x.f = f;
  unsigned r = x.u + 0x7fffu + ((x.u >> 16) & 1u);
  return (u16)(r >> 16);
}
__device__ __forceinline__ float b2f(u16 h) {
  union { unsigned u; float f; } x; x.u = ((unsigned)h) << 16; return x.f;
}

#define GLOAD_LDS16(g, l) __builtin_amdgcn_global_load_lds( \
    (const __attribute__((address_space(1))) unsigned int*)(g), \
    (__attribute__((address_space(3))) unsigned int*)(l), 16, 0, 0)

// ---------------- CSR build ----------------
__global__ void hist_kernel(const int* __restrict__ rows, const float* __restrict__ vals,
                            int* __restrict__ counts, float* __restrict__ rowsum, int E) {
  int e = blockIdx.x * 256 + threadIdx.x;
  if (e < E) {
    int r = rows[e];
    atomicAdd(&counts[r], 1);
    atomicAdd(&rowsum[r], vals[e]);
  }
}

__global__ void scan_bsum(const int* __restrict__ counts, int* __restrict__ bsum, int n) {
  __shared__ int s[256];
  int t = threadIdx.x;
  int gi = blockIdx.x * 256 + t;
  s[t] = (gi < n) ? counts[gi] : 0;
  __syncthreads();
  for (int d = 128; d > 0; d >>= 1) {
    if (t < d) s[t] += s[t + d];
    __syncthreads();
  }
  if (t == 0) bsum[blockIdx.x] = s[0];
}

__global__ void scan_partials(int* __restrict__ bsum, int nb) {
  __shared__ int s[256];
  int t = threadIdx.x;
  int v = (t < nb) ? bsum[t] : 0;
  s[t] = v;
  __syncthreads();
  for (int d = 1; d < 256; d <<= 1) {
    int x = (t >= d) ? s[t - d] : 0;
    __syncthreads();
    s[t] += x;
    __syncthreads();
  }
  if (t < nb) bsum[t] = s[t] - v;  // exclusive
}

__global__ void scan_final(const int* __restrict__ counts, const int* __restrict__ bsum,
                           int* __restrict__ offs, int n) {
  __shared__ int s[256];
  int t = threadIdx.x;
  int gi = blockIdx.x * 256 + t;
  int v = (gi < n) ? counts[gi] : 0;
  s[t] = v;
  __syncthreads();
  for (int d = 1; d < 256; d <<= 1) {
    int x = (t >= d) ? s[t - d] : 0;
    __syncthreads();
    s[t] += x;
    __syncthreads();
  }
  if (gi <= n) offs[gi] = bsum[blockIdx.x] + s[t] - v;
}

__global__ void scatter_kernel(const int* __restrict__ rows, const int* __restrict__ cols,
                               const float* __restrict__ vals, const int* __restrict__ offs,
                               int* __restrict__ cursor, int* __restrict__ ecol,
                               float* __restrict__ ev2, int E) {
  int e = blockIdx.x * 256 + threadIdx.x;
  if (e < E) {
    int r = rows[e];
    int p = offs[r] + atomicAdd(&cursor[r], 1);
    ecol[p] = cols[e];
    ev2[p] = vals[e];
  }
}

// ---------------- repack: fea f32 [NN][1024] -> Xs [32][NN][32] bf16 (compact slices) --------
__global__ void repack_fea(const float* __restrict__ fea, u16* __restrict__ Xs) {
  int g = blockIdx.x * 256 + threadIdx.x;  // g < NN*128, each thread does 8 cols
  if (g >= NN * 128) return;
  int node = g >> 7;
  int k = g & 127;
  const float* src = fea + (size_t)node * 1024 + k * 8;
  float4 f0 = *(const float4*)src;
  float4 f1 = *(const float4*)(src + 4);
  u16x8 o;
  o[0] = f2b(f0.x); o[1] = f2b(f0.y); o[2] = f2b(f0.z); o[3] = f2b(f0.w);
  o[4] = f2b(f1.x); o[5] = f2b(f1.y); o[6] = f2b(f1.z); o[7] = f2b(f1.w);
  int pass = k >> 2;
  int off = (k & 3) * 8;
  *(u16x8*)(Xs + (size_t)pass * (NN * 32) + (size_t)node * 32 + off) = o;
}

// W [K][N] f32 -> Wt [N][K] bf16
__global__ void transpose_conv(const float* __restrict__ W, u16* __restrict__ Wt, int K, int N) {
  __shared__ float tile[32][33];
  int bx = blockIdx.x * 32;  // n
  int by = blockIdx.y * 32;  // k
  int tx = threadIdx.x;
  int ty = threadIdx.y;
  for (int i = 0; i < 32; i += 8) tile[ty + i][tx] = W[(size_t)(by + ty + i) * N + bx + tx];
  __syncthreads();
  for (int i = 0; i < 32; i += 8) Wt[(size_t)(bx + ty + i) * K + by + tx] = f2b(tile[tx][ty + i]);
}

// ---------------- GEMM 256x256, BK=64, 8 waves, dbuf + counted vmcnt + swizzled LDS ------------
// C[M,N] = A[M,K] @ Bt[N,K]^T (+rowsum*bias, relu). bf16 in/out, f32 accum.
// sliced=1: write output into compact slices [col/32][NN][32] (for spmm4 gathers).
__global__ __launch_bounds__(512, 2)
void gemm256(const u16* __restrict__ A, const u16* __restrict__ Bt,
             const float* __restrict__ bias, const float* __restrict__ rowsum,
             u16* __restrict__ C, int M, int N, int K, int relu, int nbx, int sliced) {
  __shared__ __align__(16) u16 As[2][256 * 64];
  __shared__ __align__(16) u16 Bs[2][256 * 64];

  // bijective XCD swizzle (m204), N-fast logical order
  const int p = blockIdx.x, total = gridDim.x;
  const int q = total >> 3, r8 = total & 7;
  const int xcd = p & 7, slot_ = p >> 3;
  const int l = (xcd < r8 ? xcd * (q + 1) : r8 * (q + 1) + (xcd - r8) * q) + slot_;
  const int bm = (l / nbx) * 256;
  const int bn = (l % nbx) * 256;

  const int tid = threadIdx.x;
  const int lane = tid & 63;
  const int wid = tid >> 6;     // 0..7
  const int wm = wid >> 2;      // 0..1  -> 128-row half
  const int wn = wid & 3;       // 0..3  -> 64-col quarter
  const int l15 = lane & 15, lg = lane >> 4;

  const int xcol = (tid & 7) ^ ((tid >> 3) & 7);
  const u16* gA = A + (size_t)(bm + (tid >> 3)) * K + xcol * 8;
  const u16* gB = Bt + (size_t)(bn + (tid >> 3)) * K + xcol * 8;
  const size_t rowstep = (size_t)64 * K;

  f32x4 acc[8][4];
#pragma unroll
  for (int i = 0; i < 8; i++)
#pragma unroll
    for (int j = 0; j < 4; j++)
#pragma unroll
      for (int k = 0; k < 4; k++) acc[i][j][k] = 0.f;

  const int NT = K >> 6;

#define STAGE(kt, b)                                                           \
  {                                                                            \
    const u16* sa = gA + (size_t)(kt) * 64;                                    \
    const u16* sb = gB + (size_t)(kt) * 64;                                    \
    u16* da = &As[b][0] + tid * 8;                                             \
    u16* db = &Bs[b][0] + tid * 8;                                             \
    GLOAD_LDS16(sa, da);                                                       \
    GLOAD_LDS16(sa + rowstep, da + 4096);                                      \
    GLOAD_LDS16(sa + 2 * rowstep, da + 8192);                                  \
    GLOAD_LDS16(sa + 3 * rowstep, da + 12288);                                 \
    GLOAD_LDS16(sb, db);                                                       \
    GLOAD_LDS16(sb + rowstep, db + 4096);                                      \
    GLOAD_LDS16(sb + 2 * rowstep, db + 8192);                                  \
    GLOAD_LDS16(sb + 3 * rowstep, db + 12288);                                 \
  }

  STAGE(0, 0);  // prologue

  for (int u = 0; u < NT; u++) {
    const int cb = u & 1;
    if (u + 1 < NT) {
      STAGE(u + 1, cb ^ 1);
      asm volatile("s_waitcnt vmcnt(8)" ::: "memory");  // tile u landed; u+1 in flight
    } else {
      asm volatile("s_waitcnt vmcnt(0)" ::: "memory");  // last tile
    }
    __builtin_amdgcn_s_barrier();  // all waves' tile-u loads landed

    const u16* ab = &As[cb][0];
    const u16* bb = &Bs[cb][0];

    bf16x8 bf[4][2];
#pragma unroll
    for (int n = 0; n < 4; n++)
#pragma unroll
      for (int s = 0; s < 2; s++) {
        int row = wn * 64 + n * 16 + l15;
        int slot = (s * 4 + lg) ^ (row & 7);
        bf[n][s] = *(const bf16x8*)&bb[row * 64 + slot * 8];
      }
    bf16x8 af0[4][2];
#pragma unroll
    for (int m = 0; m < 4; m++)
#pragma unroll
      for (int s = 0; s < 2; s++) {
        int row = wm * 128 + m * 16 + l15;
        int slot = (s * 4 + lg) ^ (row & 7);
        af0[m][s] = *(const bf16x8*)&ab[row * 64 + slot * 8];
      }
    __builtin_amdgcn_s_setprio(1);
#pragma unroll
    for (int m = 0; m < 4; m++)
#pragma unroll
      for (int n = 0; n < 4; n++) {
        acc[m][n] = __builtin_amdgcn_mfma_f32_16x16x32_bf16(af0[m][0], bf[n][0], acc[m][n], 0, 0, 0);
        acc[m][n] = __builtin_amdgcn_mfma_f32_16x16x32_bf16(af0[m][1], bf[n][1], acc[m][n], 0, 0, 0);
      }
    __builtin_amdgcn_s_setprio(0);
    bf16x8 af1[4][2];
#pragma unroll
    for (int m = 0; m < 4; m++)
#pragma unroll
      for (int s = 0; s < 2; s++) {
        int row = wm * 128 + (m + 4) * 16 + l15;
        int slot = (s * 4 + lg) ^ (row & 7);
        af1[m][s] = *(const bf16x8*)&ab[row * 64 + slot * 8];
      }
    asm volatile("s_waitcnt lgkmcnt(0)" ::: "memory");  // all buf-cb reads in regs
    __builtin_amdgcn_s_barrier();  // release: next iter may stage into buf cb
    __builtin_amdgcn_s_setprio(1);
#pragma unroll
    for (int m = 0; m < 4; m++)
#pragma unroll
      for (int n = 0; n < 4; n++) {
        acc[m + 4][n] = __builtin_amdgcn_mfma_f32_16x16x32_bf16(af1[m][0], bf[n][0], acc[m + 4][n], 0, 0, 0);
        acc[m + 4][n] = __builtin_amdgcn_mfma_f32_16x16x32_bf16(af1[m][1], bf[n][1], acc[m + 4][n], 0, 0, 0);
      }
    __builtin_amdgcn_s_setprio(0);
  }
#undef STAGE

  // epilogue
  float bs[4];
#pragma unroll
  for (int n = 0; n < 4; n++) bs[n] = bias[bn + wn * 64 + n * 16 + l15];
#pragma unroll
  for (int m = 0; m < 8; m++) {
    int rowb = bm + wm * 128 + m * 16 + lg * 4;
#pragma unroll
    for (int j = 0; j < 4; j++) {
      int row = rowb + j;
      if (row < M) {
        float rs = rowsum ? rowsum[row] : 1.0f;
#pragma unroll
        for (int n = 0; n < 4; n++) {
          int col = bn + wn * 64 + n * 16 + l15;
          float v = acc[m][n][j] + rs * bs[n];
          if (relu) v = fmaxf(v, 0.f);
          if (!sliced) {
            C[(size_t)row * N + col] = f2b(v);
          } else {
            C[(size_t)(col >> 5) * ((size_t)NN * 32) + (size_t)row * 32 + (col & 31)] = f2b(v);
          }
        }
      }
    }
  }
}

// ---------------- SpMM v4 (pass-sliced, L2-resident) ----------------
// Xs: compact slices [NPASS][NN][32] bf16 (3.2 MB each — fits per-XCD L2).
// Grid = NPASS * (NN/16), 1024-thr blocks (16 nodes, 1/wave). blockIdx order is
// pass-major so each slice is temporally hot; within a pass, m204 chunking maps
// each XCD to a contiguous node range so its CSR edge window streams in its L2.
// Wave layout: 4 edges (e2) x 16 lanes (c16, 2 cols each, 4B gather -> 64B/edge).
template <int RELU, int OUTF32>
__global__ __launch_bounds__(1024)
void spmm4(const int* __restrict__ offs, const int* __restrict__ ecol,
           const float* __restrict__ ev, const u16* __restrict__ Xs,
           void* __restrict__ outp, int stride) {
  const int wid = threadIdx.x >> 6;
  const int lane = threadIdx.x & 63;
  const int e2 = lane >> 4;
  const int c16 = lane & 15;
  const int bpp = NN / 16;                 // 3125 blocks per pass
  const int pass = blockIdx.x / bpp;
  const int b = blockIdx.x % bpp;
  const int q = bpp >> 3, r = bpp & 7;     // 390, 5
  const int xcd = b & 7, slot = b >> 3;
  const int lb = (xcd < r ? xcd * (q + 1) : r * (q + 1) + (xcd - r) * q) + slot;
  const int node = lb * 16 + wid;

  const u16* __restrict__ Xp = Xs + (size_t)pass * (NN * 32) + c16 * 2;
  const int s0 = offs[node], e0 = offs[node + 1];
  float a0 = 0.f, a1 = 0.f;
  int j = s0;
  for (; j + 8 <= e0; j += 8) {
    int ca = ecol[j + e2], cb = ecol[j + 4 + e2];
    float va = ev[j + e2], vb = ev[j + 4 + e2];
    unsigned pa = *(const unsigned*)(Xp + (size_t)ca * 32);
    unsigned pb = *(const unsigned*)(Xp + (size_t)cb * 32);
    a0 += va * b2f((u16)pa);
    a1 += va * b2f((u16)(pa >> 16));
    a0 += vb * b2f((u16)pb);
    a1 += vb * b2f((u16)(pb >> 16));
  }
  if (j + 4 <= e0) {
    int ca = ecol[j + e2];
    float va = ev[j + e2];
    unsigned pa = *(const unsigned*)(Xp + (size_t)ca * 32);
    a0 += va * b2f((u16)pa);
    a1 += va * b2f((u16)(pa >> 16));
    j += 4;
  }
  if (e2 < e0 - j) {
    int ca = ecol[j + e2];
    float va = ev[j + e2];
    unsigned pa = *(const unsigned*)(Xp + (size_t)ca * 32);
    a0 += va * b2f((u16)pa);
    a1 += va * b2f((u16)(pa >> 16));
  }
  // reduce over the 4 edge groups (lanes l, l+16, l+32, l+48)
  a0 += __shfl_xor(a0, 16);
  a1 += __shfl_xor(a1, 16);
  a0 += __shfl_xor(a0, 32);
  a1 += __shfl_xor(a1, 32);
  if (RELU) { a0 = fmaxf(a0, 0.f); a1 = fmaxf(a1, 0.f); }
  if (e2 == 0) {
    if (OUTF32) {
      float2 st; st.x = a0; st.y = a1;
      *(float2*)((float*)outp + (size_t)node * stride + pass * 32 + c16 * 2) = st;
    } else {
      ushort2 st; st.x = f2b(a0); st.y = f2b(a1);
      *(ushort2*)((u16*)outp + (size_t)node * stride + pass * 32 + c16 * 2) = st;
    }
  }
}

extern "C" void kernel_launch(void* const* d_in, const int* in_sizes, int n_in,
                              void* d_out, int out_size, void* d_ws, size_t ws_size,
                              hipStream_t stream) {
  const float* fea = (const float*)d_in[0];
  const int* ei = (const int*)d_in[1];
  const float* ev = (const float*)d_in[2];
  const float* W1 = (const float*)d_in[3];
  const float* b1 = (const float*)d_in[4];
  const float* W2 = (const float*)d_in[5];
  const float* b2 = (const float*)d_in[6];
  const float* W3 = (const float*)d_in[7];
  const float* b3 = (const float*)d_in[8];
  const int E = in_sizes[1] / 2;
  const int* erow = ei;
  const int* ecol_in = ei + E;

  char* w = (char*)d_ws;
  auto alloc = [&](size_t bytes) {
    char* p = w;
    w += (bytes + 255) & ~(size_t)255;
    return p;
  };
  u16* fea_b = (u16*)alloc((size_t)NPAD * 1024 * 2);  // Xs1 slices, later h2 row-major
  u16* bufB  = (u16*)alloc((size_t)NPAD * 1024 * 2);  // agg0 row-major, later t3 slices
  u16* h1_b  = (u16*)alloc((size_t)NPAD * 2048 * 2);  // h1 row-major
  u16* t2_b  = (u16*)alloc((size_t)NPAD * 1024 * 2);  // t2 slices
  u16* W1t = (u16*)alloc((size_t)2048 * 1024 * 2);
  u16* W2t = (u16*)alloc((size_t)1024 * 2048 * 2);
  u16* W3t = (u16*)alloc((size_t)512 * 1024 * 2);
  float* rowsum = (float*)alloc((size_t)NN * 4);
  int* counts = (int*)alloc((size_t)NN * 4);
  int* cursor = (int*)alloc((size_t)NN * 4);
  int* offs = (int*)alloc((size_t)(NN + 1) * 4);
  int* ecol = (int*)alloc((size_t)E * 4);
  float* ev2 = (float*)alloc((size_t)E * 4);
  int* bsum = (int*)alloc(256 * 4);
  (void)bsum; (void)ws_size; (void)n_in; (void)out_size;

  // zero rowsum, counts, cursor (contiguous region up to offs)
  hipMemsetAsync(rowsum, 0, (size_t)((char*)offs - (char*)rowsum), stream);

  const int eb = (E + 255) / 256;
  const int nb = (NN + 256) / 256;  // covers gi = NN inclusive
  hist_kernel<<<eb, 256, 0, stream>>>(erow, ev, counts, rowsum, E);
  scan_bsum<<<nb, 256, 0, stream>>>(counts, bsum, NN);
  scan_partials<<<1, 256, 0, stream>>>(bsum, nb);
  scan_final<<<nb, 256, 0, stream>>>(counts, bsum, offs, NN);
  scatter_kernel<<<eb, 256, 0, stream>>>(erow, ecol_in, ev, offs, cursor, ecol, ev2, E);

  repack_fea<<<(NN * 128) / 256, 256, 0, stream>>>(fea, fea_b);
  dim3 tb(32, 8);
  transpose_conv<<<dim3(2048 / 32, 1024 / 32), tb, 0, stream>>>(W1, W1t, 1024, 2048);
  transpose_conv<<<dim3(1024 / 32, 2048 / 32), tb, 0, stream>>>(W2, W2t, 2048, 1024);
  transpose_conv<<<dim3(512 / 32, 1024 / 32), tb, 0, stream>>>(W3, W3t, 1024, 512);

  const int MT2 = (NN + 255) / 256;  // 196
  const int BPP = NN / 16;           // 3125
  // layer 1: agg0 = A @ fea (32 L2-resident slice passes) ; h1 = relu(agg0 @ W1 + rowsum*b1)
  spmm4<0, 0><<<32 * BPP, 1024, 0, stream>>>(offs, ecol, ev2, fea_b, bufB, 1024);
  gemm256<<<(2048 / 256) * MT2, 512, 0, stream>>>(bufB, W1t, b1, rowsum, h1_b, NN, 2048, 1024, 1, 2048 / 256, 0);
  // layer 2: t2 = h1 @ W2 + b2 (written sliced) ; h2 = relu(A @ t2)
  gemm256<<<(1024 / 256) * MT2, 512, 0, stream>>>(h1_b, W2t, b2, nullptr, t2_b, NN, 1024, 2048, 0, 1024 / 256, 1);
  spmm4<1, 0><<<32 * BPP, 1024, 0, stream>>>(offs, ecol, ev2, t2_b, fea_b, 1024);
  // layer 3: t3 = h2 @ W3 + b3 (sliced) ; out = A @ t3 (f32)
  gemm256<<<(512 / 256) * MT2, 512, 0, stream>>>(fea_b, W3t, b3, nullptr, bufB, NN, 512, 1024, 0, 512 / 256, 1);
  spmm4<0, 1><<<16 * BPP, 1024, 0, stream>>>(offs, ecol, ev2, bufB, d_out, 512);
}

// Round 8
// 2127.111 us; speedup vs baseline: 1.4797x; 1.4797x over previous
//
#include <hip/hip_runtime.h>

typedef unsigned short u16;
using bf16x8 = __attribute__((ext_vector_type(8))) short;
using u16x8  = __attribute__((ext_vector_type(8))) unsigned short;
using f32x4  = __attribute__((ext_vector_type(4))) float;

#define NN 50000
#define NPAD 50176   // 196 * 256

__device__ __forceinline__ u16 f2b(float f) {
  union { float f; unsigned u; } x; x.f = f;
  unsigned r = x.u + 0x7fffu + ((x.u >> 16) & 1u);
  return (u16)(r >> 16);
}
__device__ __forceinline__ float b2f(u16 h) {
  union { unsigned u; float f; } x; x.u = ((unsigned)h) << 16; return x.f;
}

#define GLOAD_LDS16(g, l) __builtin_amdgcn_global_load_lds( \
    (const __attribute__((address_space(1))) unsigned int*)(g), \
    (__attribute__((address_space(3))) unsigned int*)(l), 16, 0, 0)

// ---------------- CSR build ----------------
__global__ void hist_kernel(const int* __restrict__ rows, const float* __restrict__ vals,
                            int* __restrict__ counts, float* __restrict__ rowsum, int E) {
  int e = blockIdx.x * 256 + threadIdx.x;
  if (e < E) {
    int r = rows[e];
    atomicAdd(&counts[r], 1);
    atomicAdd(&rowsum[r], vals[e]);
  }
}

__global__ void scan_bsum(const int* __restrict__ counts, int* __restrict__ bsum, int n) {
  __shared__ int s[256];
  int t = threadIdx.x;
  int gi = blockIdx.x * 256 + t;
  s[t] = (gi < n) ? counts[gi] : 0;
  __syncthreads();
  for (int d = 128; d > 0; d >>= 1) {
    if (t < d) s[t] += s[t + d];
    __syncthreads();
  }
  if (t == 0) bsum[blockIdx.x] = s[0];
}

__global__ void scan_partials(int* __restrict__ bsum, int nb) {
  __shared__ int s[256];
  int t = threadIdx.x;
  int v = (t < nb) ? bsum[t] : 0;
  s[t] = v;
  __syncthreads();
  for (int d = 1; d < 256; d <<= 1) {
    int x = (t >= d) ? s[t - d] : 0;
    __syncthreads();
    s[t] += x;
    __syncthreads();
  }
  if (t < nb) bsum[t] = s[t] - v;  // exclusive
}

__global__ void scan_final(const int* __restrict__ counts, const int* __restrict__ bsum,
                           int* __restrict__ offs, int n) {
  __shared__ int s[256];
  int t = threadIdx.x;
  int gi = blockIdx.x * 256 + t;
  int v = (gi < n) ? counts[gi] : 0;
  s[t] = v;
  __syncthreads();
  for (int d = 1; d < 256; d <<= 1) {
    int x = (t >= d) ? s[t - d] : 0;
    __syncthreads();
    s[t] += x;
    __syncthreads();
  }
  if (gi <= n) offs[gi] = bsum[blockIdx.x] + s[t] - v;
}

__global__ void scatter_kernel(const int* __restrict__ rows, const int* __restrict__ cols,
                               const float* __restrict__ vals, const int* __restrict__ offs,
                               int* __restrict__ cursor, int* __restrict__ ecol,
                               float* __restrict__ ev2, int E) {
  int e = blockIdx.x * 256 + threadIdx.x;
  if (e < E) {
    int r = rows[e];
    int p = offs[r] + atomicAdd(&cursor[r], 1);
    ecol[p] = cols[e];
    ev2[p] = vals[e];
  }
}

// ---------------- conversions ----------------
__global__ void conv_f2b4(const float* __restrict__ in, u16* __restrict__ out, int n4) {
  int i = blockIdx.x * 256 + threadIdx.x;
  if (i < n4) {
    float4 f = ((const float4*)in)[i];
    ushort4 o;
    o.x = f2b(f.x); o.y = f2b(f.y); o.z = f2b(f.z); o.w = f2b(f.w);
    ((ushort4*)out)[i] = o;
  }
}

// W [K][N] f32 -> Wt [N][K] bf16
__global__ void transpose_conv(const float* __restrict__ W, u16* __restrict__ Wt, int K, int N) {
  __shared__ float tile[32][33];
  int bx = blockIdx.x * 32;  // n
  int by = blockIdx.y * 32;  // k
  int tx = threadIdx.x;
  int ty = threadIdx.y;
  for (int i = 0; i < 32; i += 8) tile[ty + i][tx] = W[(size_t)(by + ty + i) * N + bx + tx];
  __syncthreads();
  for (int i = 0; i < 32; i += 8) Wt[(size_t)(bx + ty + i) * K + by + tx] = f2b(tile[tx][ty + i]);
}

// ---------------- GEMM 256x256, BK=64, 8 waves, m201-style 4-phase K-loop ------------
// C[M,N] = A[M,K] @ Bt[N,K]^T (+rowsum*bias, relu). bf16 in/out, f32 accum.
// Per K-tile: 4 barrier-delimited phases, each {ds_read subtile || stage pair ->
// barrier -> 16 MFMA (one C-quadrant) -> barrier}. Counted vmcnt(4) at tile
// boundary (4 staging loads always in flight; never drained in the loop).
// LDS read-swizzle: 16B-slot ^= (row&7); stage pre-XORs the global source col.
__global__ __launch_bounds__(512, 2)
void gemm256(const u16* __restrict__ A, const u16* __restrict__ Bt,
             const float* __restrict__ bias, const float* __restrict__ rowsum,
             u16* __restrict__ C, int M, int N, int K, int relu, int nbx) {
  __shared__ __align__(16) u16 As[2][256 * 64];
  __shared__ __align__(16) u16 Bs[2][256 * 64];

  // bijective XCD swizzle (m204), N-fast logical order
  const int p = blockIdx.x, total = gridDim.x;
  const int q = total >> 3, r8 = total & 7;
  const int xcd = p & 7, slot_ = p >> 3;
  const int l = (xcd < r8 ? xcd * (q + 1) : r8 * (q + 1) + (xcd - r8) * q) + slot_;
  const int bm = (l / nbx) * 256;
  const int bn = (l % nbx) * 256;

  const int tid = threadIdx.x;
  const int lane = tid & 63;
  const int wid = tid >> 6;     // 0..7
  const int wm = wid >> 2;      // 0..1  -> 128-row half
  const int wn = wid & 3;       // 0..3  -> 64-col quarter
  const int l15 = lane & 15, lg = lane >> 4;

  const int xcol = (tid & 7) ^ ((tid >> 3) & 7);
  const u16* gA = A + (size_t)(bm + (tid >> 3)) * K + xcol * 8;
  const u16* gB = Bt + (size_t)(bn + (tid >> 3)) * K + xcol * 8;
  const size_t rowstep = (size_t)64 * K;

  f32x4 acc[8][4];
#pragma unroll
  for (int i = 0; i < 8; i++)
#pragma unroll
    for (int j = 0; j < 4; j++)
#pragma unroll
      for (int k = 0; k < 4; k++) acc[i][j][k] = 0.f;

  const int NT = K >> 6;

  // stage pair i of tile kt into buffer b: i=0,1 -> A halves; i=2,3 -> B halves
#define SPAIR_A(kt, b, h)                                                      \
  {                                                                            \
    const u16* s_ = gA + (size_t)(kt) * 64 + (size_t)(2 * (h)) * rowstep;      \
    u16* d_ = &As[b][0] + tid * 8 + (2 * (h)) * 4096;                          \
    GLOAD_LDS16(s_, d_);                                                       \
    GLOAD_LDS16(s_ + rowstep, d_ + 4096);                                      \
  }
#define SPAIR_B(kt, b, h)                                                      \
  {                                                                            \
    const u16* s_ = gB + (size_t)(kt) * 64 + (size_t)(2 * (h)) * rowstep;      \
    u16* d_ = &Bs[b][0] + tid * 8 + (2 * (h)) * 4096;                          \
    GLOAD_LDS16(s_, d_);                                                       \
    GLOAD_LDS16(s_ + rowstep, d_ + 4096);                                      \
  }

  // prologue: fully stage tile 0
  SPAIR_A(0, 0, 0); SPAIR_A(0, 0, 1); SPAIR_B(0, 0, 0); SPAIR_B(0, 0, 1);

  for (int u = 0; u < NT; u++) {
    const int cb = u & 1;
    const u16* ab = &As[cb][0];
    const u16* bb = &Bs[cb][0];

    // tile boundary: issue first half of next tile's stages, then counted wait
    if (u + 1 < NT) {
      SPAIR_A(u + 1, cb ^ 1, 0);
      SPAIR_A(u + 1, cb ^ 1, 1);
      asm volatile("s_waitcnt vmcnt(4)" ::: "memory");  // tile u landed; 4 in flight
    } else {
      asm volatile("s_waitcnt vmcnt(0)" ::: "memory");
    }
    __builtin_amdgcn_s_barrier();

    bf16x8 a[4][2], bqa[2][2], bqb[2][2];

    // ---- phase 1: read A0 (m0-3) + B01 (n0-1); stage B-pair0; Q(m0-3, n0-1)
#pragma unroll
    for (int m = 0; m < 4; m++) {
      int row = wm * 128 + m * 16 + l15, r7 = row & 7;
#pragma unroll
      for (int s = 0; s < 2; s++)
        a[m][s] = *(const bf16x8*)&ab[row * 64 + ((s * 4 + lg) ^ r7) * 8];
    }
#pragma unroll
    for (int n = 0; n < 2; n++) {
      int row = wn * 64 + n * 16 + l15, r7 = row & 7;
#pragma unroll
      for (int s = 0; s < 2; s++)
        bqa[n][s] = *(const bf16x8*)&bb[row * 64 + ((s * 4 + lg) ^ r7) * 8];
    }
    if (u + 1 < NT) SPAIR_B(u + 1, cb ^ 1, 0);
    __builtin_amdgcn_s_barrier();
    __builtin_amdgcn_s_setprio(1);
#pragma unroll
    for (int m = 0; m < 4; m++)
#pragma unroll
      for (int n = 0; n < 2; n++) {
        acc[m][n] = __builtin_amdgcn_mfma_f32_16x16x32_bf16(a[m][0], bqa[n][0], acc[m][n], 0, 0, 0);
        acc[m][n] = __builtin_amdgcn_mfma_f32_16x16x32_bf16(a[m][1], bqa[n][1], acc[m][n], 0, 0, 0);
      }
    __builtin_amdgcn_s_setprio(0);
    __builtin_amdgcn_s_barrier();

    // ---- phase 2: read B23 (n2-3); stage B-pair1; Q(m0-3, n2-3)
#pragma unroll
    for (int n = 0; n < 2; n++) {
      int row = wn * 64 + (n + 2) * 16 + l15, r7 = row & 7;
#pragma unroll
      for (int s = 0; s < 2; s++)
        bqb[n][s] = *(const bf16x8*)&bb[row * 64 + ((s * 4 + lg) ^ r7) * 8];
    }
    if (u + 1 < NT) SPAIR_B(u + 1, cb ^ 1, 1);
    __builtin_amdgcn_s_barrier();
    __builtin_amdgcn_s_setprio(1);
#pragma unroll
    for (int m = 0; m < 4; m++)
#pragma unroll
      for (int n = 0; n < 2; n++) {
        acc[m][n + 2] = __builtin_amdgcn_mfma_f32_16x16x32_bf16(a[m][0], bqb[n][0], acc[m][n + 2], 0, 0, 0);
        acc[m][n + 2] = __builtin_amdgcn_mfma_f32_16x16x32_bf16(a[m][1], bqb[n][1], acc[m][n + 2], 0, 0, 0);
      }
    __builtin_amdgcn_s_setprio(0);
    __builtin_amdgcn_s_barrier();

    // ---- phase 3: read A1 (m4-7, overwrite a[]); Q(m4-7, n2-3)
#pragma unroll
    for (int m = 0; m < 4; m++) {
      int row = wm * 128 + (m + 4) * 16 + l15, r7 = row & 7;
#pragma unroll
      for (int s = 0; s < 2; s++)
        a[m][s] = *(const bf16x8*)&ab[row * 64 + ((s * 4 + lg) ^ r7) * 8];
    }
    __builtin_amdgcn_s_barrier();
    __builtin_amdgcn_s_setprio(1);
#pragma unroll
    for (int m = 0; m < 4; m++)
#pragma unroll
      for (int n = 0; n < 2; n++) {
        acc[m + 4][n + 2] = __builtin_amdgcn_mfma_f32_16x16x32_bf16(a[m][0], bqb[n][0], acc[m + 4][n + 2], 0, 0, 0);
        acc[m + 4][n + 2] = __builtin_amdgcn_mfma_f32_16x16x32_bf16(a[m][1], bqb[n][1], acc[m + 4][n + 2], 0, 0, 0);
      }
    __builtin_amdgcn_s_setprio(0);
    __builtin_amdgcn_s_barrier();

    // ---- phase 4: no reads; Q(m4-7, n0-1)  (bqa still live from phase 1)
    __builtin_amdgcn_s_setprio(1);
#pragma unroll
    for (int m = 0; m < 4; m++)
#pragma unroll
      for (int n = 0; n < 2; n++) {
        acc[m + 4][n] = __builtin_amdgcn_mfma_f32_16x16x32_bf16(a[m][0], bqa[n][0], acc[m + 4][n], 0, 0, 0);
        acc[m + 4][n] = __builtin_amdgcn_mfma_f32_16x16x32_bf16(a[m][1], bqa[n][1], acc[m + 4][n], 0, 0, 0);
      }
    __builtin_amdgcn_s_setprio(0);
    // no closing barrier: next iter's boundary barrier closes the tile.
    // All buf-cb ds_reads retired by phase-3's closing barrier, so the next
    // tile's SPAIR writes (into buf cb^1) and the tile-after's (into cb, gated
    // by the next boundary barrier) cannot race the reads.
  }
#undef SPAIR_A
#undef SPAIR_B

  // epilogue
  float bs[4];
#pragma unroll
  for (int n = 0; n < 4; n++) bs[n] = bias[bn + wn * 64 + n * 16 + l15];
#pragma unroll
  for (int m = 0; m < 8; m++) {
    int rowb = bm + wm * 128 + m * 16 + lg * 4;
#pragma unroll
    for (int j = 0; j < 4; j++) {
      int row = rowb + j;
      if (row < M) {
        float rs = rowsum ? rowsum[row] : 1.0f;
#pragma unroll
        for (int n = 0; n < 4; n++) {
          int col = bn + wn * 64 + n * 16 + l15;
          float v = acc[m][n][j] + rs * bs[n];
          if (relu) v = fmaxf(v, 0.f);
          C[(size_t)row * N + col] = f2b(v);
        }
      }
    }
  }
}

// ---------------- SpMM v3 (CSR, column-blocked): out[i, c0:c0+P] = sum_e val[e] * X[col[e], c0:c0+P]
// X and outp are PRE-OFFSET by the column base; stride = full row width (elements).
// One node per 64-thread block; P = 64*VEC columns per pass. Direct gathers, no LDS.
template <int VEC, int RELU, int OUTF32>
__global__ __launch_bounds__(64)
void spmm3(const int* __restrict__ offs, const int* __restrict__ ecol,
           const float* __restrict__ ev, const u16* __restrict__ X,
           void* __restrict__ outp, int stride) {
  const int node = blockIdx.x;
  const int t = threadIdx.x;
  const int s0 = offs[node];
  const int e0 = offs[node + 1];
  float acc[VEC];
#pragma unroll
  for (int k = 0; k < VEC; k++) acc[k] = 0.f;
  const u16* __restrict__ Xc = X + (size_t)t * VEC;

  int j = s0;
  for (; j + 4 <= e0; j += 4) {
    const int c0 = ecol[j], c1 = ecol[j + 1], c2 = ecol[j + 2], c3 = ecol[j + 3];
    const float v0 = ev[j], v1 = ev[j + 1], v2 = ev[j + 2], v3 = ev[j + 3];
    u16 a0[VEC], a1[VEC], a2[VEC], a3[VEC];
    if constexpr (VEC == 8) {
      *(u16x8*)a0 = *(const u16x8*)(Xc + (size_t)c0 * stride);
      *(u16x8*)a1 = *(const u16x8*)(Xc + (size_t)c1 * stride);
      *(u16x8*)a2 = *(const u16x8*)(Xc + (size_t)c2 * stride);
      *(u16x8*)a3 = *(const u16x8*)(Xc + (size_t)c3 * stride);
    } else {
      *(ushort4*)a0 = *(const ushort4*)(Xc + (size_t)c0 * stride);
      *(ushort4*)a1 = *(const ushort4*)(Xc + (size_t)c1 * stride);
      *(ushort4*)a2 = *(const ushort4*)(Xc + (size_t)c2 * stride);
      *(ushort4*)a3 = *(const ushort4*)(Xc + (size_t)c3 * stride);
    }
#pragma unroll
    for (int k = 0; k < VEC; k++) acc[k] += v0 * b2f(a0[k]);
#pragma unroll
    for (int k = 0; k < VEC; k++) acc[k] += v1 * b2f(a1[k]);
#pragma unroll
    for (int k = 0; k < VEC; k++) acc[k] += v2 * b2f(a2[k]);
#pragma unroll
    for (int k = 0; k < VEC; k++) acc[k] += v3 * b2f(a3[k]);
  }
  for (; j < e0; j++) {
    const int c0 = ecol[j];
    const float v0 = ev[j];
    u16 a0[VEC];
    if constexpr (VEC == 8) {
      *(u16x8*)a0 = *(const u16x8*)(Xc + (size_t)c0 * stride);
    } else {
      *(ushort4*)a0 = *(const ushort4*)(Xc + (size_t)c0 * stride);
    }
#pragma unroll
    for (int k = 0; k < VEC; k++) acc[k] += v0 * b2f(a0[k]);
  }

  if (RELU) {
#pragma unroll
    for (int k = 0; k < VEC; k++) acc[k] = fmaxf(acc[k], 0.f);
  }
  if (OUTF32) {
    float* o = (float*)outp + (size_t)node * stride + (size_t)t * VEC;
#pragma unroll
    for (int k = 0; k < VEC; k += 4) {
      float4 st;
      st.x = acc[k]; st.y = acc[k + 1]; st.z = acc[k + 2]; st.w = acc[k + 3];
      *(float4*)(o + k) = st;
    }
  } else {
    u16* o = (u16*)outp + (size_t)node * stride + (size_t)t * VEC;
    if constexpr (VEC == 8) {
      u16x8 st;
#pragma unroll
      for (int k = 0; k < 8; k++) st[k] = f2b(acc[k]);
      *(u16x8*)o = st;
    } else {
      ushort4 st;
      st.x = f2b(acc[0]); st.y = f2b(acc[1]); st.z = f2b(acc[2]); st.w = f2b(acc[3]);
      *(ushort4*)o = st;
    }
  }
}

extern "C" void kernel_launch(void* const* d_in, const int* in_sizes, int n_in,
                              void* d_out, int out_size, void* d_ws, size_t ws_size,
                              hipStream_t stream) {
  const float* fea = (const float*)d_in[0];
  const int* ei = (const int*)d_in[1];
  const float* ev = (const float*)d_in[2];
  const float* W1 = (const float*)d_in[3];
  const float* b1 = (const float*)d_in[4];
  const float* W2 = (const float*)d_in[5];
  const float* b2 = (const float*)d_in[6];
  const float* W3 = (const float*)d_in[7];
  const float* b3 = (const float*)d_in[8];
  const int E = in_sizes[1] / 2;
  const int* erow = ei;
  const int* ecol_in = ei + E;

  char* w = (char*)d_ws;
  auto alloc = [&](size_t bytes) {
    char* p = w;
    w += (bytes + 255) & ~(size_t)255;
    return p;
  };
  u16* fea_b = (u16*)alloc((size_t)NPAD * 1024 * 2);  // later reused as h2
  u16* bufB  = (u16*)alloc((size_t)NPAD * 1024 * 2);  // agg0, later t3
  u16* h1_b  = (u16*)alloc((size_t)NPAD * 2048 * 2);
  u16* t2_b  = (u16*)alloc((size_t)NPAD * 1024 * 2);
  u16* W1t = (u16*)alloc((size_t)2048 * 1024 * 2);
  u16* W2t = (u16*)alloc((size_t)1024 * 2048 * 2);
  u16* W3t = (u16*)alloc((size_t)512 * 1024 * 2);
  float* rowsum = (float*)alloc((size_t)NN * 4);
  int* counts = (int*)alloc((size_t)NN * 4);
  int* cursor = (int*)alloc((size_t)NN * 4);
  int* offs = (int*)alloc((size_t)(NN + 1) * 4);
  int* ecol = (int*)alloc((size_t)E * 4);
  float* ev2 = (float*)alloc((size_t)E * 4);
  int* bsum = (int*)alloc(256 * 4);
  (void)bsum; (void)ws_size; (void)n_in; (void)out_size;

  // zero rowsum, counts, cursor (contiguous region up to offs)
  hipMemsetAsync(rowsum, 0, (size_t)((char*)offs - (char*)rowsum), stream);

  const int eb = (E + 255) / 256;
  const int nb = (NN + 256) / 256;  // covers gi = NN inclusive
  hist_kernel<<<eb, 256, 0, stream>>>(erow, ev, counts, rowsum, E);
  scan_bsum<<<nb, 256, 0, stream>>>(counts, bsum, NN);
  scan_partials<<<1, 256, 0, stream>>>(bsum, nb);
  scan_final<<<nb, 256, 0, stream>>>(counts, bsum, offs, NN);
  scatter_kernel<<<eb, 256, 0, stream>>>(erow, ecol_in, ev, offs, cursor, ecol, ev2, E);

  conv_f2b4<<<(NN * 1024 / 4 + 255) / 256, 256, 0, stream>>>(fea, fea_b, NN * 1024 / 4);
  dim3 tb(32, 8);
  transpose_conv<<<dim3(2048 / 32, 1024 / 32), tb, 0, stream>>>(W1, W1t, 1024, 2048);
  transpose_conv<<<dim3(1024 / 32, 2048 / 32), tb, 0, stream>>>(W2, W2t, 2048, 1024);
  transpose_conv<<<dim3(512 / 32, 1024 / 32), tb, 0, stream>>>(W3, W3t, 1024, 512);

  const int MT2 = (NN + 255) / 256;  // 196
  // layer 1: agg0 = A @ fea (2 column passes of 512) ; h1 = relu(agg0 @ W1 + rowsum*b1)
  spmm3<8, 0, 0><<<NN, 64, 0, stream>>>(offs, ecol, ev2, fea_b, bufB, 1024);
  spmm3<8, 0, 0><<<NN, 64, 0, stream>>>(offs, ecol, ev2, fea_b + 512, bufB + 512, 1024);
  gemm256<<<(2048 / 256) * MT2, 512, 0, stream>>>(bufB, W1t, b1, rowsum, h1_b, NN, 2048, 1024, 1, 2048 / 256);
  // layer 2: t2 = h1 @ W2 + b2 ; h2 = relu(A @ t2) (2 column passes of 512)
  gemm256<<<(1024 / 256) * MT2, 512, 0, stream>>>(h1_b, W2t, b2, nullptr, t2_b, NN, 1024, 2048, 0, 1024 / 256);
  spmm3<8, 1, 0><<<NN, 64, 0, stream>>>(offs, ecol, ev2, t2_b, fea_b, 1024);
  spmm3<8, 1, 0><<<NN, 64, 0, stream>>>(offs, ecol, ev2, t2_b + 512, fea_b + 512, 1024);
  // layer 3: t3 = h2 @ W3 + b3 ; out = A @ t3 (2 column passes of 256, f32 out)
  gemm256<<<(512 / 256) * MT2, 512, 0, stream>>>(fea_b, W3t, b3, nullptr, bufB, NN, 512, 1024, 0, 512 / 256);
  spmm3<4, 0, 1><<<NN, 64, 0, stream>>>(offs, ecol, ev2, bufB, d_out, 512);
  spmm3<4, 0, 1><<<NN, 64, 0, stream>>>(offs, ecol, ev2, bufB + 256, (float*)d_out + 256, 512);
}